// Round 3
// baseline (110.627 us; speedup 1.0000x reference)
//
#include <hip/hip_runtime.h>

// ButterflyRotation: 12 butterfly layers over rows of 4096 fp32.
// R3: register-resident. One wave = 2 rows. Layers 0-5 in-lane (lane i holds
// e = i*64+4j+k), one wave-internal LDS transpose (no barriers), layers 6-11
// in-lane (lane i holds e = i+64m). Angles from precomputed cs table.

#define DIM    4096
#define LAYERS 12
#define BATCH  8192
#define NANG   2048   // angles per layer

__global__ void __launch_bounds__(256) cs_kernel(const float* __restrict__ angles,
                                                 float2* __restrict__ cs, int n) {
    int i = blockIdx.x * blockDim.x + threadIdx.x;
    if (i < n) {
        float a = angles[i];
        cs[i] = make_float2(cosf(a), sinf(a));
    }
}

__device__ __forceinline__ void rot(float& xl, float& xr, float c, float s) {
    float nl = fmaf(s, xr, c * xl);
    float nr = fmaf(-s, xl, c * xr);
    xl = nl; xr = nr;
}

__global__ void __launch_bounds__(64, 2)
butterfly_kernel(const float* __restrict__ x, const float2* __restrict__ cs,
                 float* __restrict__ out) {
    __shared__ float lds[DIM];          // 16 KiB transpose buffer (reused per row)
    const int i = threadIdx.x;          // lane 0..63
    const long row0 = (long)blockIdx.x * 2;

    float a0[64], a1[64];               // phase-1 data: element i*64 + s

    // ---- load both rows: lane i gets elements [i*64, i*64+63] ----
    {
        const float* p0 = x + row0 * DIM + i * 64;
        const float* p1 = p0 + DIM;
        #pragma unroll
        for (int j = 0; j < 16; ++j) {
            float4 v0 = *(const float4*)(p0 + 4 * j);
            float4 v1 = *(const float4*)(p1 + 4 * j);
            a0[4*j+0] = v0.x; a0[4*j+1] = v0.y; a0[4*j+2] = v0.z; a0[4*j+3] = v0.w;
            a1[4*j+0] = v1.x; a1[4*j+1] = v1.y; a1[4*j+2] = v1.z; a1[4*j+3] = v1.w;
        }
    }

    // ---- layers 0,1 (strides 1,2): within each float4 quad ----
    {
        const float2* t0 = cs;            // layer 0 table
        const float2* t1 = cs + NANG;     // layer 1 table
        #pragma unroll
        for (int j = 0; j < 16; ++j) {
            // angle indices: a = i*32 + 2j (+1) for both layers
            float4 c0 = *(const float4*)(t0 + i * 32 + 2 * j);
            float4 c1 = *(const float4*)(t1 + i * 32 + 2 * j);
            rot(a0[4*j+0], a0[4*j+1], c0.x, c0.y); rot(a0[4*j+2], a0[4*j+3], c0.z, c0.w);
            rot(a1[4*j+0], a1[4*j+1], c0.x, c0.y); rot(a1[4*j+2], a1[4*j+3], c0.z, c0.w);
            rot(a0[4*j+0], a0[4*j+2], c1.x, c1.y); rot(a0[4*j+1], a0[4*j+3], c1.z, c1.w);
            rot(a1[4*j+0], a1[4*j+2], c1.x, c1.y); rot(a1[4*j+1], a1[4*j+3], c1.z, c1.w);
        }
    }

    // ---- layers 2..5 (strides 4..32): across quads, still in-lane ----
    // layer lp, t = 2^(lp-2): pairs (jl, jl+t); angle base
    //   a = i*32 + ((jl>>(lp-1))<<lp) + (jl&(t-1))*4  (+k for k=0..3)
    #pragma unroll
    for (int lp = 2; lp <= 5; ++lp) {
        const int t = 1 << (lp - 2);
        const float2* tl = cs + lp * NANG;
        #pragma unroll
        for (int jj = 0; jj < 8; ++jj) {
            const int jl = ((jj & ~(t - 1)) << 1) | (jj & (t - 1));
            const int jr = jl + t;
            const int ab = i * 32 + ((jl >> (lp - 1)) << lp) + (jl & (t - 1)) * 4;
            float4 cA = *(const float4*)(tl + ab);      // angles ab, ab+1
            float4 cB = *(const float4*)(tl + ab + 2);  // angles ab+2, ab+3
            rot(a0[4*jl+0], a0[4*jr+0], cA.x, cA.y);
            rot(a0[4*jl+1], a0[4*jr+1], cA.z, cA.w);
            rot(a0[4*jl+2], a0[4*jr+2], cB.x, cB.y);
            rot(a0[4*jl+3], a0[4*jr+3], cB.z, cB.w);
            rot(a1[4*jl+0], a1[4*jr+0], cA.x, cA.y);
            rot(a1[4*jl+1], a1[4*jr+1], cA.z, cA.w);
            rot(a1[4*jl+2], a1[4*jr+2], cB.x, cB.y);
            rot(a1[4*jl+3], a1[4*jr+3], cB.z, cB.w);
        }
    }

    // ---- wave-internal transpose via LDS (no barriers, lgkmcnt only) ----
    // pos(e) = (e & ~63) | ((e&63) ^ ((e>>6)&31)); both write and read are
    // <=2-way bank patterns (free). Same-wave WAR/RAW fenced with lgkmcnt(0).
    float d0[64], d1[64];               // phase-2 data: element i + 64m
    {
        #pragma unroll
        for (int s = 0; s < 64; ++s)
            lds[(i << 6) + (s ^ (i & 31))] = a0[s];
        asm volatile("s_waitcnt lgkmcnt(0)" ::: "memory");
        #pragma unroll
        for (int m = 0; m < 64; ++m)
            d0[m] = lds[(m << 6) + (i ^ (m & 31))];
        asm volatile("s_waitcnt lgkmcnt(0)" ::: "memory");
        #pragma unroll
        for (int s = 0; s < 64; ++s)
            lds[(i << 6) + (s ^ (i & 31))] = a1[s];
        asm volatile("s_waitcnt lgkmcnt(0)" ::: "memory");
        #pragma unroll
        for (int m = 0; m < 64; ++m)
            d1[m] = lds[(m << 6) + (i ^ (m & 31))];
        asm volatile("s_waitcnt lgkmcnt(0)" ::: "memory");
    }

    // ---- layers 6..11 (strides 64..2048): in-lane across m ----
    // layer l, t = 2^(l-6): pairs (ml, ml+t); angle
    //   a = ((ml>>(l-5))<<l) + ((ml&(t-1))<<6) + i   (coalesced across lanes)
    #pragma unroll
    for (int l = 6; l <= 11; ++l) {
        const int t = 1 << (l - 6);
        const float2* tl = cs + l * NANG;
        #pragma unroll
        for (int mm = 0; mm < 32; ++mm) {
            const int ml = ((mm & ~(t - 1)) << 1) | (mm & (t - 1));
            const int mr = ml + t;
            const int a = ((ml >> (l - 5)) << l) + ((ml & (t - 1)) << 6) + i;
            float2 c = tl[a];
            rot(d0[ml], d0[mr], c.x, c.y);
            rot(d1[ml], d1[mr], c.x, c.y);
        }
    }

    // ---- store: lane i holds elements i + 64m; 256B-contiguous per instr ----
    {
        float* q0 = out + row0 * DIM + i;
        float* q1 = q0 + DIM;
        #pragma unroll
        for (int m = 0; m < 64; ++m) {
            q0[m << 6] = d0[m];
            q1[m << 6] = d1[m];
        }
    }
}

extern "C" void kernel_launch(void* const* d_in, const int* in_sizes, int n_in,
                              void* d_out, int out_size, void* d_ws, size_t ws_size,
                              hipStream_t stream) {
    (void)in_sizes; (void)n_in; (void)out_size; (void)ws_size;
    const float* x      = (const float*)d_in[0];
    const float* angles = (const float*)d_in[1];
    float* out = (float*)d_out;
    float2* cs = (float2*)d_ws;   // 12*2048*8 B = 196 KiB scratch

    const int n = LAYERS * NANG;
    cs_kernel<<<(n + 255) / 256, 256, 0, stream>>>(angles, cs, n);
    butterfly_kernel<<<BATCH / 2, 64, 0, stream>>>(x, cs, out);
}